// Round 19
// baseline (387.077 us; speedup 1.0000x reference)
//
#include <hip/hip_runtime.h>
#include <hip/hip_bf16.h>
#include <stdint.h>

#define T_SEQ 2048
#define H_DIM 3584
#define NQH 28
#define NKVH 4
#define HD 128
#define KV_N 512          // NKVH*HD
#define QKV_N 4608        // 3584 + 512 + 512
#define K_DIM 3584

typedef __bf16 bf16x8 __attribute__((ext_vector_type(8)));
typedef float f32x4 __attribute__((ext_vector_type(4)));
typedef float f32x16 __attribute__((ext_vector_type(16)));
typedef uint u32x4 __attribute__((ext_vector_type(4)));

#if __has_builtin(__builtin_amdgcn_exp2f)
#define EXP2 __builtin_amdgcn_exp2f
#else
#define EXP2 exp2f
#endif

__device__ __forceinline__ ushort f2b(float f) {
  uint x = __builtin_bit_cast(uint, f);
  x += 0x7fffu + ((x >> 16) & 1u);
  return (ushort)(x >> 16);
}
__device__ __forceinline__ float b2f(ushort u) {
  return __builtin_bit_cast(float, (uint)u << 16);
}

__device__ __forceinline__ void gload_lds16(const void* gptr, void* ldsptr) {
  __builtin_amdgcn_global_load_lds(
      (const __attribute__((address_space(1))) uint32_t*)gptr,
      (__attribute__((address_space(3))) uint32_t*)ldsptr, 16, 0, 0);
}

#define FULL_BARRIER()                              \
  do {                                              \
    asm volatile("" ::: "memory");                  \
    __builtin_amdgcn_s_barrier();                   \
    asm volatile("" ::: "memory");                  \
  } while (0)

template <int N>
__device__ __forceinline__ void waitcnt_vm() {
  if constexpr (N == 0) asm volatile("s_waitcnt vmcnt(0)" ::: "memory");
  else if constexpr (N == 5) asm volatile("s_waitcnt vmcnt(5)" ::: "memory");
  else if constexpr (N == 6) asm volatile("s_waitcnt vmcnt(6)" ::: "memory");
  else if constexpr (N == 8) asm volatile("s_waitcnt vmcnt(8)" ::: "memory");
  else static_assert(N == 0 || N == 5 || N == 6 || N == 8, "unsupported vmcnt");
}

// pack two f32 -> one u32 of 2 bf16 (lo = a, hi = b)
__device__ __forceinline__ uint cvtpk(float a, float b) {
  uint r;
  asm("v_cvt_pk_bf16_f32 %0, %1, %2" : "=v"(r) : "v"(a), "v"(b));
  return r;
}
__device__ __forceinline__ void swap32(uint& a, uint& b) {
#if __has_builtin(__builtin_amdgcn_permlane32_swap)
  typedef int i32x2 __attribute__((ext_vector_type(2)));
  i32x2 r = __builtin_amdgcn_permlane32_swap((int)a, (int)b, false, false);
  a = (uint)r.x; b = (uint)r.y;
#else
  int lo = ((threadIdx.x & 63) < 32);
  uint sa = __shfl_xor((int)a, 32, 64);
  uint sb = __shfl_xor((int)b, 32, 64);
  uint na = lo ? a : sb;
  uint nb = lo ? sa : b;
  a = na; b = nb;
#endif
}

// ---------------- fused preprocessing: cast + bias concat + 4 transposes + counter zero ----------------
__global__ __launch_bounds__(256) void prep_kernel(
    const float* __restrict__ hs, ushort* __restrict__ hs_b,
    const float* __restrict__ bq, const float* __restrict__ bk,
    const float* __restrict__ bv, float* __restrict__ biasb,
    const float* __restrict__ Wq, const float* __restrict__ Wk,
    const float* __restrict__ Wv, const float* __restrict__ Wo,
    ushort* __restrict__ WqkvT, ushort* __restrict__ WoT,
    int* __restrict__ Cnt) {
  __shared__ float tile[32][33];
  const int b = blockIdx.x;
  if (b < 7168) {
    int i = (b * 256 + threadIdx.x) * 4;
    float4 v = *(const float4*)(hs + i);
    ushort4 o = make_ushort4(f2b(v.x), f2b(v.y), f2b(v.z), f2b(v.w));
    *(ushort4*)(hs_b + i) = o;
    return;
  }
  if (b < 7186) {
    int i = (b - 7168) * 256 + threadIdx.x;
    float v;
    if (i < H_DIM) v = bq[i];
    else if (i < H_DIM + KV_N) v = bk[i - H_DIM];
    else v = bv[i - H_DIM - KV_N];
    biasb[i] = v;
    return;
  }
  if (b == 7186) {
    if (threadIdx.x < 128) Cnt[threadIdx.x] = 0;
    return;
  }
  const int rel0 = b - 7187;
  const float* W; ushort* WT; int N; int rel;
  if (rel0 < 12544)      { W = Wq; WT = WqkvT;                                  N = H_DIM; rel = rel0; }
  else if (rel0 < 14336) { W = Wk; WT = WqkvT + (size_t)H_DIM * K_DIM;          N = KV_N;  rel = rel0 - 12544; }
  else if (rel0 < 16128) { W = Wv; WT = WqkvT + (size_t)(H_DIM + KV_N) * K_DIM; N = KV_N;  rel = rel0 - 14336; }
  else                   { W = Wo; WT = WoT;                                    N = H_DIM; rel = rel0 - 16128; }
  const int nblk = N / 32;
  const int n0 = (rel % nblk) * 32, k0 = (rel / nblk) * 32;
  const int tx = threadIdx.x & 31, ty = threadIdx.x >> 5;  // 32 x 8
#pragma unroll
  for (int j = 0; j < 4; ++j)
    tile[ty + j * 8][tx] = W[(size_t)(k0 + ty + j * 8) * N + n0 + tx];
  __syncthreads();
#pragma unroll
  for (int j = 0; j < 4; ++j)
    WT[(size_t)(n0 + ty + j * 8) * K_DIM + k0 + tx] = f2b(tile[tx][ty + j * 8]);
}

// ---------------- single-barrier 3-slot pipelined GEMM (R12-proven) ----------------
// OUT_MODE 0: f32 out, no bias. 1: bf16 out + bias. 2: KV mode — K col-blocks
// (c0 < 512) -> bf16+bias to Cout; V col-blocks (c0 >= 512) -> bf16+bias written
// TRANSPOSED into VTout (each thread's 4 acc rows = 4 consecutive s -> ushort4).
template <int BM, int BN, int OUT_MODE>
__global__ __launch_bounds__((BM / 64) * (BN / 64) * 64, (BM / 64) * (BN / 64) / 4)
void gemm_pipe_kernel(const ushort* __restrict__ A, const ushort* __restrict__ BT,
                      const float* __restrict__ bias, void* __restrict__ Cout,
                      ushort* __restrict__ VTout, int ldC, int K) {
  constexpr int WM = BM / 64, WN = BN / 64;
  constexpr int T = WM * WN * 64;
  constexpr int LA = BM * 8 / T;   // 16B loads/thread for a BMx64 A-tile
  constexpr int LB = BN * 8 / T;
  constexpr int LT = LA + LB;
  __shared__ __align__(16) ushort As[3][BM * 64];
  __shared__ __align__(16) ushort Bs[3][BN * 64];
  const int tid = threadIdx.x;
  const int lane = tid & 63;
  const int w = tid >> 6;
  const int wr = w / WN, wc = w % WN;
  const int g4 = lane >> 4, l16 = lane & 15;
  const int r0 = blockIdx.y * BM, c0 = blockIdx.x * BN;
  const int nk = K >> 6;

  f32x4 acc[4][4];
#pragma unroll
  for (int a = 0; a < 4; ++a)
#pragma unroll
    for (int b = 0; b < 4; ++b) acc[a][b] = f32x4{0.f, 0.f, 0.f, 0.f};

  auto stageA = [&](int s, int t) {
#pragma unroll
    for (int j = 0; j < LA; ++j) {
      int idx = j * T + tid;  // granule index
      int row = idx >> 3;     // 8 granules per 128B row
      int g = idx & 7;
      const ushort* src = A + (size_t)(r0 + row) * K + t * 64 + (g ^ (row & 7)) * 8;
      gload_lds16(src, (char*)As[s] + idx * 16);
    }
  };
  auto stageB = [&](int s, int t) {
#pragma unroll
    for (int j = 0; j < LB; ++j) {
      int idx = j * T + tid;
      int row = idx >> 3;
      int g = idx & 7;
      const ushort* src = BT + (size_t)(c0 + row) * K + t * 64 + (g ^ (row & 7)) * 8;
      gload_lds16(src, (char*)Bs[s] + idx * 16);
    }
  };

  // prologue: tiles 0 and 1; wait for tile 0 (tile 1's LT loads stay in flight)
  stageA(0, 0); stageB(0, 0);
  stageA(1, 1); stageB(1, 1);
  waitcnt_vm<LT>();
  FULL_BARRIER();

  for (int t = 0; t < nk; ++t) {
    const int s = t % 3;
    const int sp = (t + 2) % 3;
    const bool pf = (t + 2 < nk);
    const char* Asl = (const char*)As[s];
    const char* Bsl = (const char*)Bs[s];

    bf16x8 af[2][4], bf[2][4];
#pragma unroll
    for (int kk = 0; kk < 2; ++kk) {
#pragma unroll
      for (int mi = 0; mi < 4; ++mi) {
        int row = wr * 64 + mi * 16 + l16;
        int g = (kk * 4 + g4) ^ (row & 7);
        af[kk][mi] = *(const bf16x8*)(Asl + row * 128 + g * 16);
      }
#pragma unroll
      for (int ni = 0; ni < 4; ++ni) {
        int row = wc * 64 + ni * 16 + l16;
        int g = (kk * 4 + g4) ^ (row & 7);
        bf[kk][ni] = *(const bf16x8*)(Bsl + row * 128 + g * 16);
      }
    }
    if (pf) { stageA(sp, t + 2); stageB(sp, t + 2); }

    __builtin_amdgcn_s_setprio(1);
#pragma unroll
    for (int kk = 0; kk < 2; ++kk)
#pragma unroll
      for (int mi = 0; mi < 4; ++mi)
#pragma unroll
        for (int ni = 0; ni < 4; ++ni)
          acc[mi][ni] = __builtin_amdgcn_mfma_f32_16x16x32_bf16(af[kk][mi], bf[kk][ni],
                                                               acc[mi][ni], 0, 0, 0);
    __builtin_amdgcn_s_setprio(0);

    if (t + 1 < nk) {
      if (pf) waitcnt_vm<LT>();   // tile t+1 landed; tile t+2's LT loads in flight
      else    waitcnt_vm<0>();
      FULL_BARRIER();
    }
  }

  // epilogue
  if (OUT_MODE == 2 && c0 >= 512) {
    // V columns: write transposed into VT[vc][s] (4 consecutive s per frag -> ushort4)
#pragma unroll
    for (int mi = 0; mi < 4; ++mi) {
#pragma unroll
      for (int ni = 0; ni < 4; ++ni) {
        int colr = c0 + wc * 64 + ni * 16 + l16;  // 512..1023
        int vc = colr - 512;                      // kh*128 + d
        float bv = bias[colr];
        int s0r = r0 + wr * 64 + mi * 16 + g4 * 4;
        ushort4 o;
        o.x = f2b(acc[mi][ni][0] + bv);
        o.y = f2b(acc[mi][ni][1] + bv);
        o.z = f2b(acc[mi][ni][2] + bv);
        o.w = f2b(acc[mi][ni][3] + bv);
        *(ushort4*)(VTout + (size_t)vc * T_SEQ + s0r) = o;
      }
    }
    return;
  }
#pragma unroll
  for (int mi = 0; mi < 4; ++mi) {
#pragma unroll
    for (int ni = 0; ni < 4; ++ni) {
      int col = c0 + wc * 64 + ni * 16 + l16;
      float bv = (OUT_MODE >= 1) ? bias[col] : 0.f;
#pragma unroll
      for (int i = 0; i < 4; ++i) {
        int row = r0 + wr * 64 + mi * 16 + g4 * 4 + i;
        float v = acc[mi][ni][i] + bv;
        if (OUT_MODE >= 1)
          ((ushort*)Cout)[(size_t)row * ldC + col] = f2b(v);
        else
          ((float*)Cout)[(size_t)row * ldC + col] = v;
      }
    }
  }
}

// ---------------- RoPE only (V-transpose now done by KV GEMM epilogue) ----------------
__global__ __launch_bounds__(256) void rope_kernel(ushort* __restrict__ QKV,
                                                   const int* __restrict__ pos_ids) {
  int t = blockIdx.x;
  float pos = (float)pos_ids[t];
  int d = threadIdx.x & 63;
  float inv = expf(-0.2158673524f * (float)d);  // theta^(-d/64), ln(1e6)/64
  float fr = pos * inv;
  float s, c;
  sincosf(fr, &s, &c);
  ushort* row = QKV + (size_t)t * QKV_N;
  for (int head = threadIdx.x >> 6; head < 32; head += 4) {
    int c1 = head * 128 + d, c2 = c1 + 64;
    float x1 = b2f(row[c1]), x2 = b2f(row[c2]);
    row[c1] = f2b(x1 * c - x2 * s);
    row[c2] = f2b(x2 * c + x1 * s);
  }
}

// ---------------- flash attention v12: R14 pipeline + fused last-block combine ----------------
__global__ __launch_bounds__(448) void attn_kernel(const ushort* __restrict__ QKV,
                                                   const ushort* __restrict__ VT,
                                                   ushort* __restrict__ O,
                                                   float* __restrict__ Pacc,
                                                   float* __restrict__ Pml,
                                                   int* __restrict__ Cnt) {
  __shared__ __align__(16) char Ssm[3][32768];
  __shared__ int lastflag;
  const int tid = threadIdx.x;
  const int lane = tid & 63;
  const int w = tid >> 6;        // 0..6 = q-head within kv-group
  const int q = lane & 31;
  const int h = lane >> 5;
  const int kh = blockIdx.x;
  const int x = blockIdx.y;      // rank 0..95, heavy first
  int c8, lo, hi, ntot, split, half;
  if (x < 64) {
    c8 = 63 - (x >> 1);
    half = x & 1;
    split = 1;
    ntot = (c8 >> 1) + 1;
    int mid = (ntot + 1) >> 1;
    lo = half ? mid : 0;
    hi = half ? ntot : mid;
  } else {
    c8 = 95 - x;
    half = 0;
    split = 0;
    ntot = (c8 >> 1) + 1;
    lo = 0;
    hi = ntot;
  }
  const int hq = kh * 7 + w;
  const int t0w = c8 * 32;

  const float qs = 0.12751744f;
  bf16x8 qf[8];
  {
    const ushort* qrow = QKV + (size_t)(t0w + q) * QKV_N + hq * 128;
#pragma unroll
    for (int cc = 0; cc < 8; ++cc) {
      bf16x8 v = *(const bf16x8*)(qrow + cc * 16 + h * 8);
#pragma unroll
      for (int j = 0; j < 8; ++j) v[j] = (__bf16)((float)v[j] * qs);
      qf[cc] = v;
    }
  }

  f32x16 acc[4];
#pragma unroll
  for (int db = 0; db < 4; ++db) acc[db] = f32x16{};
  float m = -3e38f, lsum = 0.f;

  const ushort* Kg = QKV + H_DIM + kh * 128;
  const ushort* VTh = VT + (size_t)kh * 128 * T_SEQ;

  auto stage = [&](int bi, int s0) {
#pragma unroll
    for (int rnd = 0; rnd < 5; ++rnd) {
      int gi = rnd * 448 + tid;
      if (gi >= 2048) gi -= 2048;
      const ushort* src;
      if (gi < 1024) {
        int row = gi >> 4, g = gi & 15;
        src = Kg + (size_t)(s0 + row) * QKV_N + (g ^ (row & 15)) * 8;
      } else {
        int gv = gi - 1024;
        int row = gv >> 3, g = gv & 7;
        src = VTh + (size_t)row * T_SEQ + s0 + (g ^ (row & 7)) * 8;
      }
      gload_lds16(src, Ssm[bi] + gi * 16);
    }
  };

  stage(0, lo * 64);
  if (lo + 1 < hi) {
    stage(1, (lo + 1) * 64);
    waitcnt_vm<5>();
  } else {
    waitcnt_vm<0>();
  }
  FULL_BARRIER();

  for (int sb = lo; sb < hi; ++sb) {
    const int s0 = sb * 64;
    const int s = (sb - lo) % 3;
    const bool pf = (sb + 2 < hi);
    if (pf) stage((sb - lo + 2) % 3, (sb + 2) * 64);

    const char* Kb = Ssm[s];
    const char* Vb = Ssm[s] + 16384;
    const int swzk = q & 15;
    f32x16 sa0 = {}, sa1 = {};
#pragma unroll
    for (int cc = 0; cc < 8; ++cc) {
      int gk = ((cc * 2 + h) ^ swzk) * 16;
      bf16x8 kf0 = *(const bf16x8*)(Kb + q * 256 + gk);
      bf16x8 kf1 = *(const bf16x8*)(Kb + (32 + q) * 256 + gk);
      sa0 = __builtin_amdgcn_mfma_f32_32x32x16_bf16(kf0, qf[cc], sa0, 0, 0, 0);
      sa1 = __builtin_amdgcn_mfma_f32_32x32x16_bf16(kf1, qf[cc], sa1, 0, 0, 0);
    }

    if (sb == ntot - 1) {
      const int t = t0w + q;
#pragma unroll
      for (int r = 0; r < 16; ++r) {
        int kl = (r & 3) + 8 * (r >> 2) + 4 * h;
        if (s0 + kl > t) sa0[r] = -1e30f;
        if (s0 + 32 + kl > t) sa1[r] = -1e30f;
      }
    }

    float pmax = -3e38f;
#pragma unroll
    for (int r = 0; r < 16; ++r) pmax = fmaxf(pmax, fmaxf(sa0[r], sa1[r]));
    pmax = fmaxf(pmax, __shfl_xor(pmax, 32, 64));
    if (__any(pmax > m + 8.f)) {
      float mn = fmaxf(m, pmax);
      float rs = EXP2(m - mn);
      m = mn;
      lsum *= rs;
#pragma unroll
      for (int db = 0; db < 4; ++db)
#pragma unroll
        for (int r = 0; r < 16; ++r) acc[db][r] *= rs;
    }
    float psum = 0.f;
#pragma unroll
    for (int r = 0; r < 16; ++r) { sa0[r] = EXP2(sa0[r] - m); psum += sa0[r]; }
#pragma unroll
    for (int r = 0; r < 16; ++r) { sa1[r] = EXP2(sa1[r] - m); psum += sa1[r]; }
    lsum += psum;

    const int swzv = q & 7;
#pragma unroll
    for (int c = 0; c < 4; ++c) {
      const f32x16& P = (c < 2) ? sa0 : sa1;
      const int e = c & 1;
      uint a0 = cvtpk(P[8 * e + 0], P[8 * e + 1]);
      uint a1 = cvtpk(P[8 * e + 2], P[8 * e + 3]);
      uint a2 = cvtpk(P[8 * e + 4], P[8 * e + 5]);
      uint a3 = cvtpk(P[8 * e + 6], P[8 * e + 7]);
      swap32(a0, a2);
      swap32(a1, a3);
      u32x4 pw = {a0, a1, a2, a3};
      bf16x8 pf2 = __builtin_bit_cast(bf16x8, pw);
      int gv = ((c * 2 + h) ^ swzv) * 16;
#pragma unroll
      for (int db = 0; db < 4; ++db) {
        bf16x8 vfr = *(const bf16x8*)(Vb + (db * 32 + q) * 128 + gv);
        acc[db] = __builtin_amdgcn_mfma_f32_32x32x16_bf16(vfr, pf2, acc[db], 0, 0, 0);
      }
    }

    if (sb + 1 < hi) {
      if (pf) waitcnt_vm<5>();
      else    waitcnt_vm<0>();
      FULL_BARRIER();
    }
  }

  float lt = lsum + __shfl_xor(lsum, 32, 64);
  if (!split) {
    float inv = 1.f / lt;
    ushort* orow = O + (size_t)(t0w + q) * H_DIM + hq * 128;
#pragma unroll
    for (int db = 0; db < 4; ++db) {
#pragma unroll
      for (int rg = 0; rg < 4; ++rg) {
        ushort4 o;
        o.x = f2b(acc[db][rg * 4 + 0] * inv);
        o.y = f2b(acc[db][rg * 4 + 1] * inv);
        o.z = f2b(acc[db][rg * 4 + 2] * inv);
        o.w = f2b(acc[db][rg * 4 + 3] * inv);
        *(ushort4*)(orow + db * 32 + rg * 8 + h * 4) = o;
      }
    }
    return;
  }
  // split: write partials, then last-finishing block combines all 7 heads
  const size_t e2 = ((size_t)(kh * 32 + (c8 - 32)) * 7 + w) * 2 + half;
  float* pa = Pacc + e2 * 4096 + (size_t)q * 128;
#pragma unroll
  for (int db = 0; db < 4; ++db) {
#pragma unroll
    for (int rg = 0; rg < 4; ++rg) {
      f32x4 o = {acc[db][rg * 4 + 0], acc[db][rg * 4 + 1],
                 acc[db][rg * 4 + 2], acc[db][rg * 4 + 3]};
      *(f32x4*)(pa + db * 32 + rg * 8 + h * 4) = o;
    }
  }
  if (h == 0) {
    Pml[e2 * 64 + q] = m;
    Pml[e2 * 64 + 32 + q] = lt;
  }
  __threadfence();  // release: partials visible device-wide before the count
  if (tid == 0) {
    int old = atomicAdd(&Cnt[kh * 32 + (c8 - 32)], 1);
    lastflag = (old == 1);
  }
  __syncthreads();
  if (!lastflag) return;
  __threadfence();  // acquire: see the other block's partials
  const size_t eg = (size_t)(kh * 32 + (c8 - 32)) * 7;
  for (int unit = tid; unit < 896; unit += 448) {
    const int wh = unit >> 7;        // head 0..6
    const int rc = unit & 127;
    const int r = rc >> 2, cg = rc & 3;
    const size_t e = eg + wh;
    const float m0 = Pml[(e * 2 + 0) * 64 + r], l0 = Pml[(e * 2 + 0) * 64 + 32 + r];
    const float m1 = Pml[(e * 2 + 1) * 64 + r], l1 = Pml[(e * 2 + 1) * 64 + 32 + r];
    const float mm = fmaxf(m0, m1);
    const float w0 = exp2f(m0 - mm), w1 = exp2f(m1 - mm);
    const float inv = 1.f / (w0 * l0 + w1 * l1);
    const float* a0 = Pacc + (e * 2 + 0) * 4096 + (size_t)r * 128 + cg * 32;
    const float* a1 = Pacc + (e * 2 + 1) * 4096 + (size_t)r * 128 + cg * 32;
    ushort* orow = O + (size_t)(c8 * 32 + r) * H_DIM + (kh * 7 + wh) * 128 + cg * 32;
#pragma unroll
    for (int j = 0; j < 8; ++j) {
      f32x4 v0 = *(const f32x4*)(a0 + j * 4);
      f32x4 v1 = *(const f32x4*)(a1 + j * 4);
      ushort4 o;
      o.x = f2b((w0 * v0[0] + w1 * v1[0]) * inv);
      o.y = f2b((w0 * v0[1] + w1 * v1[1]) * inv);
      o.z = f2b((w0 * v0[2] + w1 * v1[2]) * inv);
      o.w = f2b((w0 * v0[3] + w1 * v1[3]) * inv);
      *(ushort4*)(orow + j * 4) = o;
    }
  }
}

extern "C" void kernel_launch(void* const* d_in, const int* in_sizes, int n_in,
                              void* d_out, int out_size, void* d_ws, size_t ws_size,
                              hipStream_t stream) {
  const float* hs = (const float*)d_in[0];
  const int* pos = (const int*)d_in[1];
  const float* Wq = (const float*)d_in[2];
  const float* bq = (const float*)d_in[3];
  const float* Wk = (const float*)d_in[4];
  const float* bk = (const float*)d_in[5];
  const float* Wv = (const float*)d_in[6];
  const float* bv = (const float*)d_in[7];
  const float* Wo = (const float*)d_in[8];
  float* out = (float*)d_out;

  char* p = (char*)d_ws;
  ushort* hs_b = (ushort*)p;  p += (size_t)T_SEQ * H_DIM * 2;
  ushort* WqkvT = (ushort*)p; p += (size_t)QKV_N * H_DIM * 2;
  ushort* WoT = (ushort*)p;   p += (size_t)H_DIM * H_DIM * 2;
  float* biasb = (float*)p;   p += (size_t)QKV_N * 4;
  ushort* QKV = (ushort*)p;   p += (size_t)T_SEQ * QKV_N * 2;
  ushort* VT = (ushort*)p;    p += (size_t)NKVH * HD * T_SEQ * 2;
  ushort* Obuf = (ushort*)p;  p += (size_t)T_SEQ * H_DIM * 2;
  int* Cnt = (int*)p;         p += 128 * sizeof(int);

  // partial buffers alias the WqkvT region (dead after the QKV GEMMs,
  // rewritten every replay by prep_kernel -> graph-safe)
  float* Pacc = (float*)WqkvT;                   // 1792 * 4096 f32 = 29.36 MB
  float* Pml = Pacc + (size_t)1792 * 4096;       // 1792 * 64 f32 = 459 KB

  prep_kernel<<<7187 + 28672, 256, 0, stream>>>(hs, hs_b, bq, bk, bv, biasb,
                                                Wq, Wk, Wv, Wo, WqkvT, WoT, Cnt);

  // Q-projection: C[:, 0:3584] of QKV (224 blocks, <= 1 round)
  gemm_pipe_kernel<256, 128, 1><<<dim3(H_DIM / 128, T_SEQ / 256), 512, 0, stream>>>(
      hs_b, WqkvT, biasb, QKV, nullptr, QKV_N, K_DIM);
  // KV-projection (128 blocks): K -> QKV cols 3584..4095; V -> VT directly (transposed)
  gemm_pipe_kernel<128, 128, 2><<<dim3((2 * KV_N) / 128, T_SEQ / 128), 256, 0, stream>>>(
      hs_b, WqkvT + (size_t)H_DIM * K_DIM, biasb + H_DIM, QKV + H_DIM, VT, QKV_N, K_DIM);

  rope_kernel<<<T_SEQ, 256, 0, stream>>>(QKV, pos);
  attn_kernel<<<dim3(NKVH, 96), 448, 0, stream>>>(QKV, VT, Obuf, Pacc, Pml, Cnt);

  // output projection (224 blocks)
  gemm_pipe_kernel<256, 128, 0><<<dim3(H_DIM / 128, T_SEQ / 256), 512, 0, stream>>>(
      Obuf, WoT, nullptr, out, nullptr, H_DIM, K_DIM);
}

// Round 20
// 269.317 us; speedup vs baseline: 1.4373x; 1.4373x over previous
//
#include <hip/hip_runtime.h>
#include <hip/hip_bf16.h>
#include <stdint.h>

#define T_SEQ 2048
#define H_DIM 3584
#define NQH 28
#define NKVH 4
#define HD 128
#define KV_N 512          // NKVH*HD
#define QKV_N 4608        // 3584 + 512 + 512
#define K_DIM 3584

typedef __bf16 bf16x8 __attribute__((ext_vector_type(8)));
typedef float f32x4 __attribute__((ext_vector_type(4)));
typedef float f32x16 __attribute__((ext_vector_type(16)));
typedef uint u32x4 __attribute__((ext_vector_type(4)));

#if __has_builtin(__builtin_amdgcn_exp2f)
#define EXP2 __builtin_amdgcn_exp2f
#else
#define EXP2 exp2f
#endif

__device__ __forceinline__ ushort f2b(float f) {
  uint x = __builtin_bit_cast(uint, f);
  x += 0x7fffu + ((x >> 16) & 1u);
  return (ushort)(x >> 16);
}
__device__ __forceinline__ float b2f(ushort u) {
  return __builtin_bit_cast(float, (uint)u << 16);
}

__device__ __forceinline__ void gload_lds16(const void* gptr, void* ldsptr) {
  __builtin_amdgcn_global_load_lds(
      (const __attribute__((address_space(1))) uint32_t*)gptr,
      (__attribute__((address_space(3))) uint32_t*)ldsptr, 16, 0, 0);
}

#define FULL_BARRIER()                              \
  do {                                              \
    asm volatile("" ::: "memory");                  \
    __builtin_amdgcn_s_barrier();                   \
    asm volatile("" ::: "memory");                  \
  } while (0)

template <int N>
__device__ __forceinline__ void waitcnt_vm() {
  if constexpr (N == 0) asm volatile("s_waitcnt vmcnt(0)" ::: "memory");
  else if constexpr (N == 5) asm volatile("s_waitcnt vmcnt(5)" ::: "memory");
  else if constexpr (N == 6) asm volatile("s_waitcnt vmcnt(6)" ::: "memory");
  else if constexpr (N == 8) asm volatile("s_waitcnt vmcnt(8)" ::: "memory");
  else static_assert(N == 0 || N == 5 || N == 6 || N == 8, "unsupported vmcnt");
}

// pack two f32 -> one u32 of 2 bf16 (lo = a, hi = b)
__device__ __forceinline__ uint cvtpk(float a, float b) {
  uint r;
  asm("v_cvt_pk_bf16_f32 %0, %1, %2" : "=v"(r) : "v"(a), "v"(b));
  return r;
}
__device__ __forceinline__ void swap32(uint& a, uint& b) {
#if __has_builtin(__builtin_amdgcn_permlane32_swap)
  typedef int i32x2 __attribute__((ext_vector_type(2)));
  i32x2 r = __builtin_amdgcn_permlane32_swap((int)a, (int)b, false, false);
  a = (uint)r.x; b = (uint)r.y;
#else
  int lo = ((threadIdx.x & 63) < 32);
  uint sa = __shfl_xor((int)a, 32, 64);
  uint sb = __shfl_xor((int)b, 32, 64);
  uint na = lo ? a : sb;
  uint nb = lo ? sa : b;
  a = na; b = nb;
#endif
}

// ---------------- fused preprocessing: cast + bias concat + all 4 weight transposes ----------------
__global__ __launch_bounds__(256) void prep_kernel(
    const float* __restrict__ hs, ushort* __restrict__ hs_b,
    const float* __restrict__ bq, const float* __restrict__ bk,
    const float* __restrict__ bv, float* __restrict__ biasb,
    const float* __restrict__ Wq, const float* __restrict__ Wk,
    const float* __restrict__ Wv, const float* __restrict__ Wo,
    ushort* __restrict__ WqkvT, ushort* __restrict__ WoT) {
  __shared__ float tile[32][33];
  const int b = blockIdx.x;
  if (b < 7168) {
    int i = (b * 256 + threadIdx.x) * 4;
    float4 v = *(const float4*)(hs + i);
    ushort4 o = make_ushort4(f2b(v.x), f2b(v.y), f2b(v.z), f2b(v.w));
    *(ushort4*)(hs_b + i) = o;
    return;
  }
  if (b < 7186) {
    int i = (b - 7168) * 256 + threadIdx.x;
    float v;
    if (i < H_DIM) v = bq[i];
    else if (i < H_DIM + KV_N) v = bk[i - H_DIM];
    else v = bv[i - H_DIM - KV_N];
    biasb[i] = v;
    return;
  }
  const int rel0 = b - 7186;
  const float* W; ushort* WT; int N; int rel;
  if (rel0 < 12544)      { W = Wq; WT = WqkvT;                                  N = H_DIM; rel = rel0; }
  else if (rel0 < 14336) { W = Wk; WT = WqkvT + (size_t)H_DIM * K_DIM;          N = KV_N;  rel = rel0 - 12544; }
  else if (rel0 < 16128) { W = Wv; WT = WqkvT + (size_t)(H_DIM + KV_N) * K_DIM; N = KV_N;  rel = rel0 - 14336; }
  else                   { W = Wo; WT = WoT;                                    N = H_DIM; rel = rel0 - 16128; }
  const int nblk = N / 32;
  const int n0 = (rel % nblk) * 32, k0 = (rel / nblk) * 32;
  const int tx = threadIdx.x & 31, ty = threadIdx.x >> 5;  // 32 x 8
#pragma unroll
  for (int j = 0; j < 4; ++j)
    tile[ty + j * 8][tx] = W[(size_t)(k0 + ty + j * 8) * N + n0 + tx];
  __syncthreads();
#pragma unroll
  for (int j = 0; j < 4; ++j)
    WT[(size_t)(n0 + ty + j * 8) * K_DIM + k0 + tx] = f2b(tile[tx][ty + j * 8]);
}

// ---------------- single-barrier 3-slot pipelined GEMM (R12-proven) ----------------
// OUT_MODE 0: f32 out, no bias. 1: bf16 out + bias. 2: KV mode — K col-blocks
// (c0 < 512) -> bf16+bias to Cout; V col-blocks (c0 >= 512) -> bf16+bias written
// TRANSPOSED into VTout (R19-verified correct).
template <int BM, int BN, int OUT_MODE>
__global__ __launch_bounds__((BM / 64) * (BN / 64) * 64, (BM / 64) * (BN / 64) / 4)
void gemm_pipe_kernel(const ushort* __restrict__ A, const ushort* __restrict__ BT,
                      const float* __restrict__ bias, void* __restrict__ Cout,
                      ushort* __restrict__ VTout, int ldC, int K) {
  constexpr int WM = BM / 64, WN = BN / 64;
  constexpr int T = WM * WN * 64;
  constexpr int LA = BM * 8 / T;   // 16B loads/thread for a BMx64 A-tile
  constexpr int LB = BN * 8 / T;
  constexpr int LT = LA + LB;
  __shared__ __align__(16) ushort As[3][BM * 64];
  __shared__ __align__(16) ushort Bs[3][BN * 64];
  const int tid = threadIdx.x;
  const int lane = tid & 63;
  const int w = tid >> 6;
  const int wr = w / WN, wc = w % WN;
  const int g4 = lane >> 4, l16 = lane & 15;
  const int r0 = blockIdx.y * BM, c0 = blockIdx.x * BN;
  const int nk = K >> 6;

  f32x4 acc[4][4];
#pragma unroll
  for (int a = 0; a < 4; ++a)
#pragma unroll
    for (int b = 0; b < 4; ++b) acc[a][b] = f32x4{0.f, 0.f, 0.f, 0.f};

  auto stageA = [&](int s, int t) {
#pragma unroll
    for (int j = 0; j < LA; ++j) {
      int idx = j * T + tid;  // granule index
      int row = idx >> 3;     // 8 granules per 128B row
      int g = idx & 7;
      const ushort* src = A + (size_t)(r0 + row) * K + t * 64 + (g ^ (row & 7)) * 8;
      gload_lds16(src, (char*)As[s] + idx * 16);
    }
  };
  auto stageB = [&](int s, int t) {
#pragma unroll
    for (int j = 0; j < LB; ++j) {
      int idx = j * T + tid;
      int row = idx >> 3;
      int g = idx & 7;
      const ushort* src = BT + (size_t)(c0 + row) * K + t * 64 + (g ^ (row & 7)) * 8;
      gload_lds16(src, (char*)Bs[s] + idx * 16);
    }
  };

  // prologue: tiles 0 and 1; wait for tile 0 (tile 1's LT loads stay in flight)
  stageA(0, 0); stageB(0, 0);
  stageA(1, 1); stageB(1, 1);
  waitcnt_vm<LT>();
  FULL_BARRIER();

  for (int t = 0; t < nk; ++t) {
    const int s = t % 3;
    const int sp = (t + 2) % 3;
    const bool pf = (t + 2 < nk);
    const char* Asl = (const char*)As[s];
    const char* Bsl = (const char*)Bs[s];

    bf16x8 af[2][4], bf[2][4];
#pragma unroll
    for (int kk = 0; kk < 2; ++kk) {
#pragma unroll
      for (int mi = 0; mi < 4; ++mi) {
        int row = wr * 64 + mi * 16 + l16;
        int g = (kk * 4 + g4) ^ (row & 7);
        af[kk][mi] = *(const bf16x8*)(Asl + row * 128 + g * 16);
      }
#pragma unroll
      for (int ni = 0; ni < 4; ++ni) {
        int row = wc * 64 + ni * 16 + l16;
        int g = (kk * 4 + g4) ^ (row & 7);
        bf[kk][ni] = *(const bf16x8*)(Bsl + row * 128 + g * 16);
      }
    }
    if (pf) { stageA(sp, t + 2); stageB(sp, t + 2); }

    __builtin_amdgcn_s_setprio(1);
#pragma unroll
    for (int kk = 0; kk < 2; ++kk)
#pragma unroll
      for (int mi = 0; mi < 4; ++mi)
#pragma unroll
        for (int ni = 0; ni < 4; ++ni)
          acc[mi][ni] = __builtin_amdgcn_mfma_f32_16x16x32_bf16(af[kk][mi], bf[kk][ni],
                                                               acc[mi][ni], 0, 0, 0);
    __builtin_amdgcn_s_setprio(0);

    if (t + 1 < nk) {
      if (pf) waitcnt_vm<LT>();   // tile t+1 landed; tile t+2's LT loads in flight
      else    waitcnt_vm<0>();
      FULL_BARRIER();
    }
  }

  // epilogue
  if (OUT_MODE == 2 && c0 >= 512) {
    // V columns: write transposed into VT[vc][s] (4 consecutive s per frag -> ushort4)
#pragma unroll
    for (int mi = 0; mi < 4; ++mi) {
#pragma unroll
      for (int ni = 0; ni < 4; ++ni) {
        int colr = c0 + wc * 64 + ni * 16 + l16;  // 512..1023
        int vc = colr - 512;                      // kh*128 + d
        float bv = bias[colr];
        int s0r = r0 + wr * 64 + mi * 16 + g4 * 4;
        ushort4 o;
        o.x = f2b(acc[mi][ni][0] + bv);
        o.y = f2b(acc[mi][ni][1] + bv);
        o.z = f2b(acc[mi][ni][2] + bv);
        o.w = f2b(acc[mi][ni][3] + bv);
        *(ushort4*)(VTout + (size_t)vc * T_SEQ + s0r) = o;
      }
    }
    return;
  }
#pragma unroll
  for (int mi = 0; mi < 4; ++mi) {
#pragma unroll
    for (int ni = 0; ni < 4; ++ni) {
      int col = c0 + wc * 64 + ni * 16 + l16;
      float bv = (OUT_MODE >= 1) ? bias[col] : 0.f;
#pragma unroll
      for (int i = 0; i < 4; ++i) {
        int row = r0 + wr * 64 + mi * 16 + g4 * 4 + i;
        float v = acc[mi][ni][i] + bv;
        if (OUT_MODE >= 1)
          ((ushort*)Cout)[(size_t)row * ldC + col] = f2b(v);
        else
          ((float*)Cout)[(size_t)row * ldC + col] = v;
      }
    }
  }
}

// ---------------- RoPE only (V-transpose done by KV GEMM epilogue) ----------------
__global__ __launch_bounds__(256) void rope_kernel(ushort* __restrict__ QKV,
                                                   const int* __restrict__ pos_ids) {
  int t = blockIdx.x;
  float pos = (float)pos_ids[t];
  int d = threadIdx.x & 63;
  float inv = expf(-0.2158673524f * (float)d);  // theta^(-d/64), ln(1e6)/64
  float fr = pos * inv;
  float s, c;
  sincosf(fr, &s, &c);
  ushort* row = QKV + (size_t)t * QKV_N;
  for (int head = threadIdx.x >> 6; head < 32; head += 4) {
    int c1 = head * 128 + d, c2 = c1 + 64;
    float x1 = b2f(row[c1]), x2 = b2f(row[c2]);
    row[c1] = f2b(x1 * c - x2 * s);
    row[c2] = f2b(x2 * c + x1 * s);
  }
}

// ---------------- flash attention v11 (R14-proven): counted-vmcnt 3-slot pipeline ----------------
__global__ __launch_bounds__(448) void attn_kernel(const ushort* __restrict__ QKV,
                                                   const ushort* __restrict__ VT,
                                                   ushort* __restrict__ O,
                                                   float* __restrict__ Pacc,
                                                   float* __restrict__ Pml) {
  __shared__ __align__(16) char Ssm[3][32768];
  const int tid = threadIdx.x;
  const int lane = tid & 63;
  const int w = tid >> 6;        // 0..6 = q-head within kv-group
  const int q = lane & 31;
  const int h = lane >> 5;
  const int kh = blockIdx.x;
  const int x = blockIdx.y;      // rank 0..95, heavy first
  int c8, lo, hi, ntot, split, half;
  if (x < 64) {
    c8 = 63 - (x >> 1);
    half = x & 1;
    split = 1;
    ntot = (c8 >> 1) + 1;
    int mid = (ntot + 1) >> 1;
    lo = half ? mid : 0;
    hi = half ? ntot : mid;
  } else {
    c8 = 95 - x;
    half = 0;
    split = 0;
    ntot = (c8 >> 1) + 1;
    lo = 0;
    hi = ntot;
  }
  const int hq = kh * 7 + w;
  const int t0w = c8 * 32;

  const float qs = 0.12751744f;
  bf16x8 qf[8];
  {
    const ushort* qrow = QKV + (size_t)(t0w + q) * QKV_N + hq * 128;
#pragma unroll
    for (int cc = 0; cc < 8; ++cc) {
      bf16x8 v = *(const bf16x8*)(qrow + cc * 16 + h * 8);
#pragma unroll
      for (int j = 0; j < 8; ++j) v[j] = (__bf16)((float)v[j] * qs);
      qf[cc] = v;
    }
  }

  f32x16 acc[4];
#pragma unroll
  for (int db = 0; db < 4; ++db) acc[db] = f32x16{};
  float m = -3e38f, lsum = 0.f;

  const ushort* Kg = QKV + H_DIM + kh * 128;
  const ushort* VTh = VT + (size_t)kh * 128 * T_SEQ;

  auto stage = [&](int bi, int s0) {
#pragma unroll
    for (int rnd = 0; rnd < 5; ++rnd) {
      int gi = rnd * 448 + tid;
      if (gi >= 2048) gi -= 2048;
      const ushort* src;
      if (gi < 1024) {
        int row = gi >> 4, g = gi & 15;
        src = Kg + (size_t)(s0 + row) * QKV_N + (g ^ (row & 15)) * 8;
      } else {
        int gv = gi - 1024;
        int row = gv >> 3, g = gv & 7;
        src = VTh + (size_t)row * T_SEQ + s0 + (g ^ (row & 7)) * 8;
      }
      gload_lds16(src, Ssm[bi] + gi * 16);
    }
  };

  stage(0, lo * 64);
  if (lo + 1 < hi) {
    stage(1, (lo + 1) * 64);
    waitcnt_vm<5>();
  } else {
    waitcnt_vm<0>();
  }
  FULL_BARRIER();

  for (int sb = lo; sb < hi; ++sb) {
    const int s0 = sb * 64;
    const int s = (sb - lo) % 3;
    const bool pf = (sb + 2 < hi);
    if (pf) stage((sb - lo + 2) % 3, (sb + 2) * 64);

    const char* Kb = Ssm[s];
    const char* Vb = Ssm[s] + 16384;
    const int swzk = q & 15;
    f32x16 sa0 = {}, sa1 = {};
#pragma unroll
    for (int cc = 0; cc < 8; ++cc) {
      int gk = ((cc * 2 + h) ^ swzk) * 16;
      bf16x8 kf0 = *(const bf16x8*)(Kb + q * 256 + gk);
      bf16x8 kf1 = *(const bf16x8*)(Kb + (32 + q) * 256 + gk);
      sa0 = __builtin_amdgcn_mfma_f32_32x32x16_bf16(kf0, qf[cc], sa0, 0, 0, 0);
      sa1 = __builtin_amdgcn_mfma_f32_32x32x16_bf16(kf1, qf[cc], sa1, 0, 0, 0);
    }

    if (sb == ntot - 1) {
      const int t = t0w + q;
#pragma unroll
      for (int r = 0; r < 16; ++r) {
        int kl = (r & 3) + 8 * (r >> 2) + 4 * h;
        if (s0 + kl > t) sa0[r] = -1e30f;
        if (s0 + 32 + kl > t) sa1[r] = -1e30f;
      }
    }

    float pmax = -3e38f;
#pragma unroll
    for (int r = 0; r < 16; ++r) pmax = fmaxf(pmax, fmaxf(sa0[r], sa1[r]));
    pmax = fmaxf(pmax, __shfl_xor(pmax, 32, 64));
    if (__any(pmax > m + 8.f)) {
      float mn = fmaxf(m, pmax);
      float rs = EXP2(m - mn);
      m = mn;
      lsum *= rs;
#pragma unroll
      for (int db = 0; db < 4; ++db)
#pragma unroll
        for (int r = 0; r < 16; ++r) acc[db][r] *= rs;
    }
    float psum = 0.f;
#pragma unroll
    for (int r = 0; r < 16; ++r) { sa0[r] = EXP2(sa0[r] - m); psum += sa0[r]; }
#pragma unroll
    for (int r = 0; r < 16; ++r) { sa1[r] = EXP2(sa1[r] - m); psum += sa1[r]; }
    lsum += psum;

    const int swzv = q & 7;
#pragma unroll
    for (int c = 0; c < 4; ++c) {
      const f32x16& P = (c < 2) ? sa0 : sa1;
      const int e = c & 1;
      uint a0 = cvtpk(P[8 * e + 0], P[8 * e + 1]);
      uint a1 = cvtpk(P[8 * e + 2], P[8 * e + 3]);
      uint a2 = cvtpk(P[8 * e + 4], P[8 * e + 5]);
      uint a3 = cvtpk(P[8 * e + 6], P[8 * e + 7]);
      swap32(a0, a2);
      swap32(a1, a3);
      u32x4 pw = {a0, a1, a2, a3};
      bf16x8 pf2 = __builtin_bit_cast(bf16x8, pw);
      int gv = ((c * 2 + h) ^ swzv) * 16;
#pragma unroll
      for (int db = 0; db < 4; ++db) {
        bf16x8 vfr = *(const bf16x8*)(Vb + (db * 32 + q) * 128 + gv);
        acc[db] = __builtin_amdgcn_mfma_f32_32x32x16_bf16(vfr, pf2, acc[db], 0, 0, 0);
      }
    }

    if (sb + 1 < hi) {
      if (pf) waitcnt_vm<5>();
      else    waitcnt_vm<0>();
      FULL_BARRIER();
    }
  }

  float lt = lsum + __shfl_xor(lsum, 32, 64);
  if (!split) {
    float inv = 1.f / lt;
    ushort* orow = O + (size_t)(t0w + q) * H_DIM + hq * 128;
#pragma unroll
    for (int db = 0; db < 4; ++db) {
#pragma unroll
      for (int rg = 0; rg < 4; ++rg) {
        ushort4 o;
        o.x = f2b(acc[db][rg * 4 + 0] * inv);
        o.y = f2b(acc[db][rg * 4 + 1] * inv);
        o.z = f2b(acc[db][rg * 4 + 2] * inv);
        o.w = f2b(acc[db][rg * 4 + 3] * inv);
        *(ushort4*)(orow + db * 32 + rg * 8 + h * 4) = o;
      }
    }
  } else {
    const size_t e2 = ((size_t)(kh * 32 + (c8 - 32)) * 7 + w) * 2 + half;
    float* pa = Pacc + e2 * 4096 + (size_t)q * 128;
#pragma unroll
    for (int db = 0; db < 4; ++db) {
#pragma unroll
      for (int rg = 0; rg < 4; ++rg) {
        f32x4 o = {acc[db][rg * 4 + 0], acc[db][rg * 4 + 1],
                   acc[db][rg * 4 + 2], acc[db][rg * 4 + 3]};
        *(f32x4*)(pa + db * 32 + rg * 8 + h * 4) = o;
      }
    }
    if (h == 0) {
      Pml[e2 * 64 + q] = m;
      Pml[e2 * 64 + 32 + q] = lt;
    }
  }
}

// ---------------- combine partials for split chunks (R18-proven) ----------------
__global__ __launch_bounds__(128) void combine_kernel(const float* __restrict__ Pacc,
                                                      const float* __restrict__ Pml,
                                                      ushort* __restrict__ O) {
  const int cx = blockIdx.x;       // chunk c8 = 32 + cx
  const int hq = blockIdx.y;
  const int kh = hq / 7, w = hq % 7;
  const int r = threadIdx.x >> 2;
  const int cg = threadIdx.x & 3;
  const size_t e = ((size_t)(kh * 32 + cx) * 7 + w);
  const float m0 = Pml[(e * 2 + 0) * 64 + r], l0 = Pml[(e * 2 + 0) * 64 + 32 + r];
  const float m1 = Pml[(e * 2 + 1) * 64 + r], l1 = Pml[(e * 2 + 1) * 64 + 32 + r];
  const float mm = fmaxf(m0, m1);
  const float w0 = exp2f(m0 - mm), w1 = exp2f(m1 - mm);
  const float inv = 1.f / (w0 * l0 + w1 * l1);
  const float* a0 = Pacc + (e * 2 + 0) * 4096 + (size_t)r * 128 + cg * 32;
  const float* a1 = Pacc + (e * 2 + 1) * 4096 + (size_t)r * 128 + cg * 32;
  ushort* orow = O + (size_t)((32 + cx) * 32 + r) * H_DIM + hq * 128 + cg * 32;
#pragma unroll
  for (int j = 0; j < 8; ++j) {
    f32x4 v0 = *(const f32x4*)(a0 + j * 4);
    f32x4 v1 = *(const f32x4*)(a1 + j * 4);
    ushort4 o;
    o.x = f2b((w0 * v0[0] + w1 * v1[0]) * inv);
    o.y = f2b((w0 * v0[1] + w1 * v1[1]) * inv);
    o.z = f2b((w0 * v0[2] + w1 * v1[2]) * inv);
    o.w = f2b((w0 * v0[3] + w1 * v1[3]) * inv);
    *(ushort4*)(orow + j * 4) = o;
  }
}

extern "C" void kernel_launch(void* const* d_in, const int* in_sizes, int n_in,
                              void* d_out, int out_size, void* d_ws, size_t ws_size,
                              hipStream_t stream) {
  const float* hs = (const float*)d_in[0];
  const int* pos = (const int*)d_in[1];
  const float* Wq = (const float*)d_in[2];
  const float* bq = (const float*)d_in[3];
  const float* Wk = (const float*)d_in[4];
  const float* bk = (const float*)d_in[5];
  const float* Wv = (const float*)d_in[6];
  const float* bv = (const float*)d_in[7];
  const float* Wo = (const float*)d_in[8];
  float* out = (float*)d_out;

  char* p = (char*)d_ws;
  ushort* hs_b = (ushort*)p;  p += (size_t)T_SEQ * H_DIM * 2;
  ushort* WqkvT = (ushort*)p; p += (size_t)QKV_N * H_DIM * 2;
  ushort* WoT = (ushort*)p;   p += (size_t)H_DIM * H_DIM * 2;
  float* biasb = (float*)p;   p += (size_t)QKV_N * 4;
  ushort* QKV = (ushort*)p;   p += (size_t)T_SEQ * QKV_N * 2;
  ushort* VT = (ushort*)p;    p += (size_t)NKVH * HD * T_SEQ * 2;
  ushort* Obuf = (ushort*)p;  p += (size_t)T_SEQ * H_DIM * 2;

  // partial buffers alias the WqkvT region (dead after the QKV GEMMs,
  // rewritten every replay by prep_kernel -> graph-safe)
  float* Pacc = (float*)WqkvT;                   // 1792 * 4096 f32 = 29.36 MB
  float* Pml = Pacc + (size_t)1792 * 4096;       // 1792 * 64 f32 = 459 KB

  prep_kernel<<<7186 + 28672, 256, 0, stream>>>(hs, hs_b, bq, bk, bv, biasb,
                                                Wq, Wk, Wv, Wo, WqkvT, WoT);

  // Q-projection: C[:, 0:3584] of QKV (224 blocks, <= 1 round)
  gemm_pipe_kernel<256, 128, 1><<<dim3(H_DIM / 128, T_SEQ / 256), 512, 0, stream>>>(
      hs_b, WqkvT, biasb, QKV, nullptr, QKV_N, K_DIM);
  // KV-projection (128 blocks): K -> QKV cols 3584..4095; V -> VT directly (transposed)
  gemm_pipe_kernel<128, 128, 2><<<dim3((2 * KV_N) / 128, T_SEQ / 128), 256, 0, stream>>>(
      hs_b, WqkvT + (size_t)H_DIM * K_DIM, biasb + H_DIM, QKV + H_DIM, VT, QKV_N, K_DIM);

  rope_kernel<<<T_SEQ, 256, 0, stream>>>(QKV, pos);
  attn_kernel<<<dim3(NKVH, 96), 448, 0, stream>>>(QKV, VT, Obuf, Pacc, Pml);
  combine_kernel<<<dim3(32, NQH), 128, 0, stream>>>(Pacc, Pml, Obuf);

  // output projection (224 blocks)
  gemm_pipe_kernel<256, 128, 0><<<dim3(H_DIM / 128, T_SEQ / 256), 512, 0, stream>>>(
      Obuf, WoT, nullptr, out, nullptr, H_DIM, K_DIM);
}

// Round 21
// 267.735 us; speedup vs baseline: 1.4457x; 1.0059x over previous
//
#include <hip/hip_runtime.h>
#include <hip/hip_bf16.h>
#include <stdint.h>

#define T_SEQ 2048
#define H_DIM 3584
#define NQH 28
#define NKVH 4
#define HD 128
#define KV_N 512          // NKVH*HD
#define QKV_N 4608        // 3584 + 512 + 512
#define K_DIM 3584

typedef __bf16 bf16x8 __attribute__((ext_vector_type(8)));
typedef float f32x4 __attribute__((ext_vector_type(4)));
typedef float f32x16 __attribute__((ext_vector_type(16)));
typedef uint u32x4 __attribute__((ext_vector_type(4)));

#if __has_builtin(__builtin_amdgcn_exp2f)
#define EXP2 __builtin_amdgcn_exp2f
#else
#define EXP2 exp2f
#endif

__device__ __forceinline__ ushort f2b(float f) {
  uint x = __builtin_bit_cast(uint, f);
  x += 0x7fffu + ((x >> 16) & 1u);
  return (ushort)(x >> 16);
}
__device__ __forceinline__ float b2f(ushort u) {
  return __builtin_bit_cast(float, (uint)u << 16);
}

__device__ __forceinline__ void gload_lds16(const void* gptr, void* ldsptr) {
  __builtin_amdgcn_global_load_lds(
      (const __attribute__((address_space(1))) uint32_t*)gptr,
      (__attribute__((address_space(3))) uint32_t*)ldsptr, 16, 0, 0);
}

#define FULL_BARRIER()                              \
  do {                                              \
    asm volatile("" ::: "memory");                  \
    __builtin_amdgcn_s_barrier();                   \
    asm volatile("" ::: "memory");                  \
  } while (0)

template <int N>
__device__ __forceinline__ void waitcnt_vm() {
  if constexpr (N == 0) asm volatile("s_waitcnt vmcnt(0)" ::: "memory");
  else if constexpr (N == 5) asm volatile("s_waitcnt vmcnt(5)" ::: "memory");
  else if constexpr (N == 6) asm volatile("s_waitcnt vmcnt(6)" ::: "memory");
  else if constexpr (N == 8) asm volatile("s_waitcnt vmcnt(8)" ::: "memory");
  else static_assert(N == 0 || N == 5 || N == 6 || N == 8, "unsupported vmcnt");
}

// pack two f32 -> one u32 of 2 bf16 (lo = a, hi = b)
__device__ __forceinline__ uint cvtpk(float a, float b) {
  uint r;
  asm("v_cvt_pk_bf16_f32 %0, %1, %2" : "=v"(r) : "v"(a), "v"(b));
  return r;
}
__device__ __forceinline__ void swap32(uint& a, uint& b) {
#if __has_builtin(__builtin_amdgcn_permlane32_swap)
  typedef int i32x2 __attribute__((ext_vector_type(2)));
  i32x2 r = __builtin_amdgcn_permlane32_swap((int)a, (int)b, false, false);
  a = (uint)r.x; b = (uint)r.y;
#else
  int lo = ((threadIdx.x & 63) < 32);
  uint sa = __shfl_xor((int)a, 32, 64);
  uint sb = __shfl_xor((int)b, 32, 64);
  uint na = lo ? a : sb;
  uint nb = lo ? sa : b;
  a = na; b = nb;
#endif
}

// ---------------- fused preprocessing: cast + bias + cos/sin table + 4 transposes ----------------
// blocks [0,7168): cast; [7168,7186): bias; [7186,7698): rope table; rest: transposes.
__global__ __launch_bounds__(256) void prep_kernel(
    const float* __restrict__ hs, ushort* __restrict__ hs_b,
    const float* __restrict__ bq, const float* __restrict__ bk,
    const float* __restrict__ bv, float* __restrict__ biasb,
    const int* __restrict__ pos_ids, float2* __restrict__ CS,
    const float* __restrict__ Wq, const float* __restrict__ Wk,
    const float* __restrict__ Wv, const float* __restrict__ Wo,
    ushort* __restrict__ WqkvT, ushort* __restrict__ WoT) {
  __shared__ float tile[32][33];
  const int b = blockIdx.x;
  if (b < 7168) {
    int i = (b * 256 + threadIdx.x) * 4;
    float4 v = *(const float4*)(hs + i);
    ushort4 o = make_ushort4(f2b(v.x), f2b(v.y), f2b(v.z), f2b(v.w));
    *(ushort4*)(hs_b + i) = o;
    return;
  }
  if (b < 7186) {
    int i = (b - 7168) * 256 + threadIdx.x;
    float v;
    if (i < H_DIM) v = bq[i];
    else if (i < H_DIM + KV_N) v = bk[i - H_DIM];
    else v = bv[i - H_DIM - KV_N];
    biasb[i] = v;
    return;
  }
  if (b < 7698) {
    int e = (b - 7186) * 256 + threadIdx.x;  // 0 .. 131071
    int t = e >> 6, fi = e & 63;
    float pos = (float)pos_ids[t];
    float inv = expf(-0.2158673524f * (float)fi);  // theta^(-fi/64)
    float s, c;
    sincosf(pos * inv, &s, &c);
    CS[e] = make_float2(c, s);
    return;
  }
  const int rel0 = b - 7698;
  const float* W; ushort* WT; int N; int rel;
  if (rel0 < 12544)      { W = Wq; WT = WqkvT;                                  N = H_DIM; rel = rel0; }
  else if (rel0 < 14336) { W = Wk; WT = WqkvT + (size_t)H_DIM * K_DIM;          N = KV_N;  rel = rel0 - 12544; }
  else if (rel0 < 16128) { W = Wv; WT = WqkvT + (size_t)(H_DIM + KV_N) * K_DIM; N = KV_N;  rel = rel0 - 14336; }
  else                   { W = Wo; WT = WoT;                                    N = H_DIM; rel = rel0 - 16128; }
  const int nblk = N / 32;
  const int n0 = (rel % nblk) * 32, k0 = (rel / nblk) * 32;
  const int tx = threadIdx.x & 31, ty = threadIdx.x >> 5;  // 32 x 8
#pragma unroll
  for (int j = 0; j < 4; ++j)
    tile[ty + j * 8][tx] = W[(size_t)(k0 + ty + j * 8) * N + n0 + tx];
  __syncthreads();
#pragma unroll
  for (int j = 0; j < 4; ++j)
    WT[(size_t)(n0 + ty + j * 8) * K_DIM + k0 + tx] = f2b(tile[tx][ty + j * 8]);
}

// ---------------- single-barrier 3-slot pipelined GEMM (R12-proven core) ----------------
// OUT_MODE 0: f32 out. 1: bf16+bias. 2: KV mode (K cols -> Cout, V cols -> VTout
// transposed). ROPE 1: apply rotary in epilogue via LDS pair-exchange + CS table
// (each block = one head: pairs (d, d^64) live in wave-column halves wc=0/1).
template <int BM, int BN, int OUT_MODE, int ROPE>
__global__ __launch_bounds__((BM / 64) * (BN / 64) * 64, (BM / 64) * (BN / 64) / 4)
void gemm_pipe_kernel(const ushort* __restrict__ A, const ushort* __restrict__ BT,
                      const float* __restrict__ bias, void* __restrict__ Cout,
                      ushort* __restrict__ VTout, const float2* __restrict__ CS,
                      int ldC, int K) {
  constexpr int WM = BM / 64, WN = BN / 64;
  constexpr int T = WM * WN * 64;
  constexpr int LA = BM * 8 / T;   // 16B loads/thread for a BMx64 A-tile
  constexpr int LB = BN * 8 / T;
  constexpr int LT = LA + LB;
  constexpr int SMEMB = 3 * (BM * 64 + BN * 64) * 2;
  static_assert(!ROPE || SMEMB >= BM * 132 * 4, "rope scratch fits");
  __shared__ __align__(16) char SMEM[SMEMB];
  ushort (*As)[BM * 64] = (ushort(*)[BM * 64])SMEM;
  ushort (*Bs)[BN * 64] = (ushort(*)[BN * 64])(SMEM + 3 * BM * 64 * 2);
  const int tid = threadIdx.x;
  const int lane = tid & 63;
  const int w = tid >> 6;
  const int wr = w / WN, wc = w % WN;
  const int g4 = lane >> 4, l16 = lane & 15;
  const int r0 = blockIdx.y * BM, c0 = blockIdx.x * BN;
  const int nk = K >> 6;

  f32x4 acc[4][4];
#pragma unroll
  for (int a = 0; a < 4; ++a)
#pragma unroll
    for (int b = 0; b < 4; ++b) acc[a][b] = f32x4{0.f, 0.f, 0.f, 0.f};

  auto stageA = [&](int s, int t) {
#pragma unroll
    for (int j = 0; j < LA; ++j) {
      int idx = j * T + tid;  // granule index
      int row = idx >> 3;     // 8 granules per 128B row
      int g = idx & 7;
      const ushort* src = A + (size_t)(r0 + row) * K + t * 64 + (g ^ (row & 7)) * 8;
      gload_lds16(src, (char*)As[s] + idx * 16);
    }
  };
  auto stageB = [&](int s, int t) {
#pragma unroll
    for (int j = 0; j < LB; ++j) {
      int idx = j * T + tid;
      int row = idx >> 3;
      int g = idx & 7;
      const ushort* src = BT + (size_t)(c0 + row) * K + t * 64 + (g ^ (row & 7)) * 8;
      gload_lds16(src, (char*)Bs[s] + idx * 16);
    }
  };

  // prologue: tiles 0 and 1; wait for tile 0 (tile 1's LT loads stay in flight)
  stageA(0, 0); stageB(0, 0);
  stageA(1, 1); stageB(1, 1);
  waitcnt_vm<LT>();
  FULL_BARRIER();

  for (int t = 0; t < nk; ++t) {
    const int s = t % 3;
    const int sp = (t + 2) % 3;
    const bool pf = (t + 2 < nk);
    const char* Asl = (const char*)As[s];
    const char* Bsl = (const char*)Bs[s];

    bf16x8 af[2][4], bf[2][4];
#pragma unroll
    for (int kk = 0; kk < 2; ++kk) {
#pragma unroll
      for (int mi = 0; mi < 4; ++mi) {
        int row = wr * 64 + mi * 16 + l16;
        int g = (kk * 4 + g4) ^ (row & 7);
        af[kk][mi] = *(const bf16x8*)(Asl + row * 128 + g * 16);
      }
#pragma unroll
      for (int ni = 0; ni < 4; ++ni) {
        int row = wc * 64 + ni * 16 + l16;
        int g = (kk * 4 + g4) ^ (row & 7);
        bf[kk][ni] = *(const bf16x8*)(Bsl + row * 128 + g * 16);
      }
    }
    if (pf) { stageA(sp, t + 2); stageB(sp, t + 2); }

    __builtin_amdgcn_s_setprio(1);
#pragma unroll
    for (int kk = 0; kk < 2; ++kk)
#pragma unroll
      for (int mi = 0; mi < 4; ++mi)
#pragma unroll
        for (int ni = 0; ni < 4; ++ni)
          acc[mi][ni] = __builtin_amdgcn_mfma_f32_16x16x32_bf16(af[kk][mi], bf[kk][ni],
                                                               acc[mi][ni], 0, 0, 0);
    __builtin_amdgcn_s_setprio(0);

    if (t + 1 < nk) {
      if (pf) waitcnt_vm<LT>();   // tile t+1 landed; tile t+2's LT loads in flight
      else    waitcnt_vm<0>();
      FULL_BARRIER();
    }
  }

  // ---- epilogue ----
  if (OUT_MODE == 2 && c0 >= 512) {
    // V columns: write transposed into VT[vc][s] (4 consecutive s per frag -> ushort4)
#pragma unroll
    for (int mi = 0; mi < 4; ++mi) {
#pragma unroll
      for (int ni = 0; ni < 4; ++ni) {
        int colr = c0 + wc * 64 + ni * 16 + l16;  // 512..1023
        int vc = colr - 512;                      // kh*128 + d
        float bv = bias[colr];
        int s0r = r0 + wr * 64 + mi * 16 + g4 * 4;
        ushort4 o;
        o.x = f2b(acc[mi][ni][0] + bv);
        o.y = f2b(acc[mi][ni][1] + bv);
        o.z = f2b(acc[mi][ni][2] + bv);
        o.w = f2b(acc[mi][ni][3] + bv);
        *(ushort4*)(VTout + (size_t)vc * T_SEQ + s0r) = o;
      }
    }
    return;
  }
  if (ROPE) {
    // rotary: exchange pair halves via LDS scratch (block-uniform path)
    FULL_BARRIER();  // all waves done reading As/Bs
    float* scr = (float*)SMEM;  // [BM][132]
#pragma unroll
    for (int mi = 0; mi < 4; ++mi) {
#pragma unroll
      for (int ni = 0; ni < 4; ++ni) {
        int colL = wc * 64 + ni * 16 + l16;
        float bv = bias[c0 + colL];
#pragma unroll
        for (int i = 0; i < 4; ++i) {
          int rowL = wr * 64 + mi * 16 + g4 * 4 + i;
          scr[rowL * 132 + colL] = acc[mi][ni][i] + bv;
        }
      }
    }
    FULL_BARRIER();
#pragma unroll
    for (int mi = 0; mi < 4; ++mi) {
#pragma unroll
      for (int ni = 0; ni < 4; ++ni) {
        int colL = wc * 64 + ni * 16 + l16;
        int fi = colL & 63;
#pragma unroll
        for (int i = 0; i < 4; ++i) {
          int rowL = wr * 64 + mi * 16 + g4 * 4 + i;
          int t = r0 + rowL;
          float2 cs = CS[t * 64 + fi];
          float self = scr[rowL * 132 + colL];
          float part = scr[rowL * 132 + (colL ^ 64)];
          float v = (colL < 64) ? (self * cs.x - part * cs.y)
                                : (self * cs.x + part * cs.y);
          ((ushort*)Cout)[(size_t)t * ldC + (c0 + colL)] = f2b(v);
        }
      }
    }
    return;
  }
#pragma unroll
  for (int mi = 0; mi < 4; ++mi) {
#pragma unroll
    for (int ni = 0; ni < 4; ++ni) {
      int col = c0 + wc * 64 + ni * 16 + l16;
      float bv = (OUT_MODE >= 1) ? bias[col] : 0.f;
#pragma unroll
      for (int i = 0; i < 4; ++i) {
        int row = r0 + wr * 64 + mi * 16 + g4 * 4 + i;
        float v = acc[mi][ni][i] + bv;
        if (OUT_MODE >= 1)
          ((ushort*)Cout)[(size_t)row * ldC + col] = f2b(v);
        else
          ((float*)Cout)[(size_t)row * ldC + col] = v;
      }
    }
  }
}

// ---------------- flash attention v11 (R14-proven): counted-vmcnt 3-slot pipeline ----------------
__global__ __launch_bounds__(448) void attn_kernel(const ushort* __restrict__ QKV,
                                                   const ushort* __restrict__ VT,
                                                   ushort* __restrict__ O,
                                                   float* __restrict__ Pacc,
                                                   float* __restrict__ Pml) {
  __shared__ __align__(16) char Ssm[3][32768];
  const int tid = threadIdx.x;
  const int lane = tid & 63;
  const int w = tid >> 6;        // 0..6 = q-head within kv-group
  const int q = lane & 31;
  const int h = lane >> 5;
  const int kh = blockIdx.x;
  const int x = blockIdx.y;      // rank 0..95, heavy first
  int c8, lo, hi, ntot, split, half;
  if (x < 64) {
    c8 = 63 - (x >> 1);
    half = x & 1;
    split = 1;
    ntot = (c8 >> 1) + 1;
    int mid = (ntot + 1) >> 1;
    lo = half ? mid : 0;
    hi = half ? ntot : mid;
  } else {
    c8 = 95 - x;
    half = 0;
    split = 0;
    ntot = (c8 >> 1) + 1;
    lo = 0;
    hi = ntot;
  }
  const int hq = kh * 7 + w;
  const int t0w = c8 * 32;

  const float qs = 0.12751744f;
  bf16x8 qf[8];
  {
    const ushort* qrow = QKV + (size_t)(t0w + q) * QKV_N + hq * 128;
#pragma unroll
    for (int cc = 0; cc < 8; ++cc) {
      bf16x8 v = *(const bf16x8*)(qrow + cc * 16 + h * 8);
#pragma unroll
      for (int j = 0; j < 8; ++j) v[j] = (__bf16)((float)v[j] * qs);
      qf[cc] = v;
    }
  }

  f32x16 acc[4];
#pragma unroll
  for (int db = 0; db < 4; ++db) acc[db] = f32x16{};
  float m = -3e38f, lsum = 0.f;

  const ushort* Kg = QKV + H_DIM + kh * 128;
  const ushort* VTh = VT + (size_t)kh * 128 * T_SEQ;

  auto stage = [&](int bi, int s0) {
#pragma unroll
    for (int rnd = 0; rnd < 5; ++rnd) {
      int gi = rnd * 448 + tid;
      if (gi >= 2048) gi -= 2048;
      const ushort* src;
      if (gi < 1024) {
        int row = gi >> 4, g = gi & 15;
        src = Kg + (size_t)(s0 + row) * QKV_N + (g ^ (row & 15)) * 8;
      } else {
        int gv = gi - 1024;
        int row = gv >> 3, g = gv & 7;
        src = VTh + (size_t)row * T_SEQ + s0 + (g ^ (row & 7)) * 8;
      }
      gload_lds16(src, Ssm[bi] + gi * 16);
    }
  };

  stage(0, lo * 64);
  if (lo + 1 < hi) {
    stage(1, (lo + 1) * 64);
    waitcnt_vm<5>();
  } else {
    waitcnt_vm<0>();
  }
  FULL_BARRIER();

  for (int sb = lo; sb < hi; ++sb) {
    const int s0 = sb * 64;
    const int s = (sb - lo) % 3;
    const bool pf = (sb + 2 < hi);
    if (pf) stage((sb - lo + 2) % 3, (sb + 2) * 64);

    const char* Kb = Ssm[s];
    const char* Vb = Ssm[s] + 16384;
    const int swzk = q & 15;
    f32x16 sa0 = {}, sa1 = {};
#pragma unroll
    for (int cc = 0; cc < 8; ++cc) {
      int gk = ((cc * 2 + h) ^ swzk) * 16;
      bf16x8 kf0 = *(const bf16x8*)(Kb + q * 256 + gk);
      bf16x8 kf1 = *(const bf16x8*)(Kb + (32 + q) * 256 + gk);
      sa0 = __builtin_amdgcn_mfma_f32_32x32x16_bf16(kf0, qf[cc], sa0, 0, 0, 0);
      sa1 = __builtin_amdgcn_mfma_f32_32x32x16_bf16(kf1, qf[cc], sa1, 0, 0, 0);
    }

    if (sb == ntot - 1) {
      const int t = t0w + q;
#pragma unroll
      for (int r = 0; r < 16; ++r) {
        int kl = (r & 3) + 8 * (r >> 2) + 4 * h;
        if (s0 + kl > t) sa0[r] = -1e30f;
        if (s0 + 32 + kl > t) sa1[r] = -1e30f;
      }
    }

    float pmax = -3e38f;
#pragma unroll
    for (int r = 0; r < 16; ++r) pmax = fmaxf(pmax, fmaxf(sa0[r], sa1[r]));
    pmax = fmaxf(pmax, __shfl_xor(pmax, 32, 64));
    if (__any(pmax > m + 8.f)) {
      float mn = fmaxf(m, pmax);
      float rs = EXP2(m - mn);
      m = mn;
      lsum *= rs;
#pragma unroll
      for (int db = 0; db < 4; ++db)
#pragma unroll
        for (int r = 0; r < 16; ++r) acc[db][r] *= rs;
    }
    float psum = 0.f;
#pragma unroll
    for (int r = 0; r < 16; ++r) { sa0[r] = EXP2(sa0[r] - m); psum += sa0[r]; }
#pragma unroll
    for (int r = 0; r < 16; ++r) { sa1[r] = EXP2(sa1[r] - m); psum += sa1[r]; }
    lsum += psum;

    const int swzv = q & 7;
#pragma unroll
    for (int c = 0; c < 4; ++c) {
      const f32x16& P = (c < 2) ? sa0 : sa1;
      const int e = c & 1;
      uint a0 = cvtpk(P[8 * e + 0], P[8 * e + 1]);
      uint a1 = cvtpk(P[8 * e + 2], P[8 * e + 3]);
      uint a2 = cvtpk(P[8 * e + 4], P[8 * e + 5]);
      uint a3 = cvtpk(P[8 * e + 6], P[8 * e + 7]);
      swap32(a0, a2);
      swap32(a1, a3);
      u32x4 pw = {a0, a1, a2, a3};
      bf16x8 pf2 = __builtin_bit_cast(bf16x8, pw);
      int gv = ((c * 2 + h) ^ swzv) * 16;
#pragma unroll
      for (int db = 0; db < 4; ++db) {
        bf16x8 vfr = *(const bf16x8*)(Vb + (db * 32 + q) * 128 + gv);
        acc[db] = __builtin_amdgcn_mfma_f32_32x32x16_bf16(vfr, pf2, acc[db], 0, 0, 0);
      }
    }

    if (sb + 1 < hi) {
      if (pf) waitcnt_vm<5>();
      else    waitcnt_vm<0>();
      FULL_BARRIER();
    }
  }

  float lt = lsum + __shfl_xor(lsum, 32, 64);
  if (!split) {
    float inv = 1.f / lt;
    ushort* orow = O + (size_t)(t0w + q) * H_DIM + hq * 128;
#pragma unroll
    for (int db = 0; db < 4; ++db) {
#pragma unroll
      for (int rg = 0; rg < 4; ++rg) {
        ushort4 o;
        o.x = f2b(acc[db][rg * 4 + 0] * inv);
        o.y = f2b(acc[db][rg * 4 + 1] * inv);
        o.z = f2b(acc[db][rg * 4 + 2] * inv);
        o.w = f2b(acc[db][rg * 4 + 3] * inv);
        *(ushort4*)(orow + db * 32 + rg * 8 + h * 4) = o;
      }
    }
  } else {
    const size_t e2 = ((size_t)(kh * 32 + (c8 - 32)) * 7 + w) * 2 + half;
    float* pa = Pacc + e2 * 4096 + (size_t)q * 128;
#pragma unroll
    for (int db = 0; db < 4; ++db) {
#pragma unroll
      for (int rg = 0; rg < 4; ++rg) {
        f32x4 o = {acc[db][rg * 4 + 0], acc[db][rg * 4 + 1],
                   acc[db][rg * 4 + 2], acc[db][rg * 4 + 3]};
        *(f32x4*)(pa + db * 32 + rg * 8 + h * 4) = o;
      }
    }
    if (h == 0) {
      Pml[e2 * 64 + q] = m;
      Pml[e2 * 64 + 32 + q] = lt;
    }
  }
}

// ---------------- combine partials for split chunks (R18-proven) ----------------
__global__ __launch_bounds__(128) void combine_kernel(const float* __restrict__ Pacc,
                                                      const float* __restrict__ Pml,
                                                      ushort* __restrict__ O) {
  const int cx = blockIdx.x;       // chunk c8 = 32 + cx
  const int hq = blockIdx.y;
  const int kh = hq / 7, w = hq % 7;
  const int r = threadIdx.x >> 2;
  const int cg = threadIdx.x & 3;
  const size_t e = ((size_t)(kh * 32 + cx) * 7 + w);
  const float m0 = Pml[(e * 2 + 0) * 64 + r], l0 = Pml[(e * 2 + 0) * 64 + 32 + r];
  const float m1 = Pml[(e * 2 + 1) * 64 + r], l1 = Pml[(e * 2 + 1) * 64 + 32 + r];
  const float mm = fmaxf(m0, m1);
  const float w0 = exp2f(m0 - mm), w1 = exp2f(m1 - mm);
  const float inv = 1.f / (w0 * l0 + w1 * l1);
  const float* a0 = Pacc + (e * 2 + 0) * 4096 + (size_t)r * 128 + cg * 32;
  const float* a1 = Pacc + (e * 2 + 1) * 4096 + (size_t)r * 128 + cg * 32;
  ushort* orow = O + (size_t)((32 + cx) * 32 + r) * H_DIM + hq * 128 + cg * 32;
#pragma unroll
  for (int j = 0; j < 8; ++j) {
    f32x4 v0 = *(const f32x4*)(a0 + j * 4);
    f32x4 v1 = *(const f32x4*)(a1 + j * 4);
    ushort4 o;
    o.x = f2b((w0 * v0[0] + w1 * v1[0]) * inv);
    o.y = f2b((w0 * v0[1] + w1 * v1[1]) * inv);
    o.z = f2b((w0 * v0[2] + w1 * v1[2]) * inv);
    o.w = f2b((w0 * v0[3] + w1 * v1[3]) * inv);
    *(ushort4*)(orow + j * 4) = o;
  }
}

extern "C" void kernel_launch(void* const* d_in, const int* in_sizes, int n_in,
                              void* d_out, int out_size, void* d_ws, size_t ws_size,
                              hipStream_t stream) {
  const float* hs = (const float*)d_in[0];
  const int* pos = (const int*)d_in[1];
  const float* Wq = (const float*)d_in[2];
  const float* bq = (const float*)d_in[3];
  const float* Wk = (const float*)d_in[4];
  const float* bk = (const float*)d_in[5];
  const float* Wv = (const float*)d_in[6];
  const float* bv = (const float*)d_in[7];
  const float* Wo = (const float*)d_in[8];
  float* out = (float*)d_out;

  char* p = (char*)d_ws;
  ushort* hs_b = (ushort*)p;  p += (size_t)T_SEQ * H_DIM * 2;
  ushort* WqkvT = (ushort*)p; p += (size_t)QKV_N * H_DIM * 2;
  ushort* WoT = (ushort*)p;   p += (size_t)H_DIM * H_DIM * 2;
  float* biasb = (float*)p;   p += (size_t)QKV_N * 4;
  ushort* QKV = (ushort*)p;   p += (size_t)T_SEQ * QKV_N * 2;
  ushort* VT = (ushort*)p;    p += (size_t)NKVH * HD * T_SEQ * 2;
  ushort* Obuf = (ushort*)p;  p += (size_t)T_SEQ * H_DIM * 2;
  float2* CS = (float2*)p;    p += (size_t)T_SEQ * 64 * sizeof(float2);

  // partial buffers alias the WqkvT region (dead after the QKV GEMMs,
  // rewritten every replay by prep_kernel -> graph-safe)
  float* Pacc = (float*)WqkvT;                   // 1792 * 4096 f32 = 29.36 MB
  float* Pml = Pacc + (size_t)1792 * 4096;       // 1792 * 64 f32 = 459 KB

  prep_kernel<<<7698 + 28672, 256, 0, stream>>>(hs, hs_b, bq, bk, bv, biasb,
                                                pos, CS, Wq, Wk, Wv, Wo, WqkvT, WoT);

  // Q-projection (224 blocks), RoPE fused in epilogue
  gemm_pipe_kernel<256, 128, 1, 1><<<dim3(H_DIM / 128, T_SEQ / 256), 512, 0, stream>>>(
      hs_b, WqkvT, biasb, QKV, nullptr, CS, QKV_N, K_DIM);
  // KV-projection (128 blocks): K -> QKV (roped); V -> VT directly (transposed)
  gemm_pipe_kernel<128, 128, 2, 1><<<dim3((2 * KV_N) / 128, T_SEQ / 128), 256, 0, stream>>>(
      hs_b, WqkvT + (size_t)H_DIM * K_DIM, biasb + H_DIM, QKV + H_DIM, VT, CS, QKV_N, K_DIM);

  attn_kernel<<<dim3(NKVH, 96), 448, 0, stream>>>(QKV, VT, Obuf, Pacc, Pml);
  combine_kernel<<<dim3(32, NQH), 128, 0, stream>>>(Pacc, Pml, Obuf);

  // output projection (224 blocks)
  gemm_pipe_kernel<256, 128, 0, 0><<<dim3(H_DIM / 128, T_SEQ / 256), 512, 0, stream>>>(
      Obuf, WoT, nullptr, out, nullptr, nullptr, H_DIM, K_DIM);
}